// Round 1
// baseline (336.498 us; speedup 1.0000x reference)
//
#include <hip/hip_runtime.h>
#include <hip/hip_bf16.h>

typedef __attribute__((ext_vector_type(8))) __bf16 bf16x8;
typedef __attribute__((ext_vector_type(4))) float f32x4;

constexpr int CI_ = 16, CO_ = 64, H_ = 256, W_ = 256;
constexpr int WTROW = 168;  // padded K (144 -> 168) in bf16 elems; 336B rows

// NCHW fp32 -> NHWC bf16: xt[n][h][w][ci]
__global__ void transform_x_kernel(const float* __restrict__ x,
                                   unsigned short* __restrict__ xt) {
  int idx = blockIdx.x * 256 + threadIdx.x;  // (n,h,w), 16*256*256 = 1,048,576
  int w = idx & 255;
  int h = (idx >> 8) & 255;
  int n = idx >> 16;
  const float* src = x + (((size_t)n * CI_) * H_ + h) * W_ + w;
  unsigned short tmp[16];
#pragma unroll
  for (int ci = 0; ci < 16; ++ci) {
    float v = src[(size_t)ci * (H_ * W_)];
    __bf16 b = (__bf16)v;
    tmp[ci] = __builtin_bit_cast(unsigned short, b);
  }
  uint4* dst = (uint4*)(xt + (size_t)idx * 16);
  dst[0] = ((uint4*)tmp)[0];
  dst[1] = ((uint4*)tmp)[1];
}

// OIHW fp32 -> wt[co][k], k = tap*16 + ci, padded/zeroed to 168
__global__ void transform_w_kernel(const float* __restrict__ Wg,
                                   unsigned short* __restrict__ wt) {
  int idx = blockIdx.x * 256 + threadIdx.x;  // 64*168 = 10752 exact
  int co = idx / WTROW;
  int kk = idx - co * WTROW;
  float v = 0.f;
  if (kk < 144) {
    int t = kk >> 4;        // tap = kh*3+kw
    int ci = kk & 15;
    v = Wg[(co * 16 + ci) * 9 + t];
  }
  __bf16 b = (__bf16)v;
  wt[idx] = __builtin_bit_cast(unsigned short, b);
}

// one block per (n,h): computes out[n][0..63][h][0..255]
__global__ __launch_bounds__(256) void conv_mfma_kernel(
    const unsigned short* __restrict__ xt, const unsigned short* __restrict__ wt,
    float* __restrict__ out) {
  __shared__ unsigned short xs[3][258][16];   // rows h-1,h,h+1; wp = w+1 (pad cols 0,257)
  __shared__ unsigned short wlds[CO_][WTROW]; // 21504 B

  int tid = threadIdx.x;
  int bid = blockIdx.x;
  int h = bid & 255;
  int n = bid >> 8;

  // stage weights: 21504 B = 1344 uint4
  {
    const uint4* src = (const uint4*)wt;
    uint4* dst = (uint4*)&wlds[0][0];
    for (int c = tid; c < 1344; c += 256) dst[c] = src[c];
  }
  // stage 3 input rows (8192 B each = 512 uint4), zero-filling out-of-range rows
  {
    const uint4* srcbase = (const uint4*)xt;  // one uint4 = 8 ci values (16B)
    for (int c = tid; c < 1536; c += 256) {
      int r = c >> 9;          // 0..2
      int off = c & 511;       // chunk within row
      int hh = h - 1 + r;
      uint4 v = make_uint4(0u, 0u, 0u, 0u);
      if (hh >= 0 && hh < 256)
        v = srcbase[(size_t)(n * 256 + hh) * 512 + off];
      *(uint4*)(&xs[r][1][0] + off * 8) = v;
    }
    if (tid < 6) {  // zero pad columns wp=0 and wp=257
      int r = tid >> 1;
      int wp = (tid & 1) ? 257 : 0;
      *(uint4*)&xs[r][wp][0] = make_uint4(0u, 0u, 0u, 0u);
      *(uint4*)&xs[r][wp][8] = make_uint4(0u, 0u, 0u, 0u);
    }
  }
  __syncthreads();

  int lane = tid & 63;
  int wave = tid >> 6;
  int col = lane & 15;  // pixel-in-tile / co-row for A
  int g = lane >> 4;    // 0..3 k-group

  f32x4 acc[4][4];
#pragma unroll
  for (int i = 0; i < 4; ++i)
#pragma unroll
    for (int j = 0; j < 4; ++j) acc[i][j] = (f32x4){0.f, 0.f, 0.f, 0.f};

  int pxb = wave * 64 + col;  // this lane's base pixel

#pragma unroll
  for (int s = 0; s < 5; ++s) {
    bf16x8 a[4];
#pragma unroll
    for (int cb = 0; cb < 4; ++cb)
      a[cb] = *(const bf16x8*)&wlds[cb * 16 + col][s * 32 + 8 * g];

    int tap = 2 * s + (g >> 1);
    if (tap > 8) tap = 8;       // k>=144: A is zero, B value irrelevant
    int kh = tap / 3;           // xs row index (dh+1)
    int kw = tap - kh * 3;      // wp offset
    int ci0 = (g & 1) * 8;

    bf16x8 b[4];
#pragma unroll
    for (int pb = 0; pb < 4; ++pb)
      b[pb] = *(const bf16x8*)&xs[kh][pxb + pb * 16 + kw][ci0];

#pragma unroll
    for (int cb = 0; cb < 4; ++cb)
#pragma unroll
      for (int pb = 0; pb < 4; ++pb)
        acc[cb][pb] = __builtin_amdgcn_mfma_f32_16x16x32_bf16(
            a[cb], b[pb], acc[cb][pb], 0, 0, 0);
  }

  // D layout: col = lane&15 (pixel), row = g*4 + reg (co within 16-block)
  size_t obase = ((size_t)n * CO_ * H_ + h) * W_;
#pragma unroll
  for (int cb = 0; cb < 4; ++cb) {
#pragma unroll
    for (int r = 0; r < 4; ++r) {
      int co = cb * 16 + g * 4 + r;
      float* dst = out + obase + (size_t)co * (H_ * W_);
#pragma unroll
      for (int pb = 0; pb < 4; ++pb) dst[pxb + pb * 16] = acc[cb][pb][r];
    }
  }
}

extern "C" void kernel_launch(void* const* d_in, const int* in_sizes, int n_in,
                              void* d_out, int out_size, void* d_ws, size_t ws_size,
                              hipStream_t stream) {
  const float* x = (const float*)d_in[0];   // [16,16,256,256]
  const float* W = (const float*)d_in[1];   // [64,16,3,3]
  float* out = (float*)d_out;               // [16,64,256,256]

  unsigned short* xt = (unsigned short*)d_ws;          // 16,777,216 bf16 = 32 MB
  unsigned short* wt = xt + (size_t)16 * 256 * 256 * 16; // 10752 bf16 (21504 B)

  transform_x_kernel<<<4096, 256, 0, stream>>>(x, xt);
  transform_w_kernel<<<42, 256, 0, stream>>>(W, wt);
  conv_mfma_kernel<<<4096, 256, 0, stream>>>(xt, wt, out);
}